// Round 1
// baseline (658.983 us; speedup 1.0000x reference)
//
#include <hip/hip_runtime.h>

#define SELU_SCALE 1.0507009873554805f
#define SELU_ALPHA 1.6732632423543772f

static __device__ __forceinline__ float leaky02(float v) {
  return v > 0.0f ? v : 0.2f * v;
}

// ---------------- GEMM: Y[n,128] = X[n,128] @ W[128,128] (fp32) ----------------
__global__ __launch_bounds__(256) void gemm128_kernel(const float* __restrict__ X,
                                                      const float* __restrict__ W,
                                                      float* __restrict__ Y, int n) {
  __shared__ float Ws[128][128];
  __shared__ float Xs[32][128];
  const int tid = threadIdx.x;
  {
    const float4* W4 = (const float4*)W;
    float4* S4 = (float4*)&Ws[0][0];
#pragma unroll
    for (int i = 0; i < 16; ++i) S4[i * 256 + tid] = W4[i * 256 + tid];
  }
  const int row0 = blockIdx.x * 32;
  {
    const float4* X4 = (const float4*)(X + (size_t)row0 * 128);
    float4* S4 = (float4*)&Xs[0][0];
    const int maxv = (n - row0) * 32;  // valid float4 count in this tile
#pragma unroll
    for (int i = 0; i < 4; ++i) {
      int idx = i * 256 + tid;
      float4 v = make_float4(0.f, 0.f, 0.f, 0.f);
      if (idx < maxv) v = X4[idx];
      S4[idx] = v;
    }
  }
  __syncthreads();
  const int c4 = (tid & 31) * 4;
  const int r0 = (tid >> 5) * 4;
  float acc[4][4];
#pragma unroll
  for (int i = 0; i < 4; ++i)
#pragma unroll
    for (int j = 0; j < 4; ++j) acc[i][j] = 0.f;

#pragma unroll 8
  for (int k4 = 0; k4 < 32; ++k4) {
    float4 xv[4];
#pragma unroll
    for (int i = 0; i < 4; ++i) xv[i] = *(const float4*)&Xs[r0 + i][k4 * 4];
#pragma unroll
    for (int j = 0; j < 4; ++j) {
      float4 w = *(const float4*)&Ws[k4 * 4 + j][c4];
#pragma unroll
      for (int i = 0; i < 4; ++i) {
        float xx = (j == 0) ? xv[i].x : (j == 1) ? xv[i].y : (j == 2) ? xv[i].z : xv[i].w;
        acc[i][0] += xx * w.x;
        acc[i][1] += xx * w.y;
        acc[i][2] += xx * w.z;
        acc[i][3] += xx * w.w;
      }
    }
  }
#pragma unroll
  for (int i = 0; i < 4; ++i) {
    int r = row0 + r0 + i;
    if (r < n)
      *(float4*)&Y[(size_t)r * 128 + c4] = make_float4(acc[i][0], acc[i][1], acc[i][2], acc[i][3]);
  }
}

// ---------------- attention scores, layer 1: per (node, head=8) ----------------
__global__ __launch_bounds__(256) void scores1_kernel(const float* __restrict__ h1,
                                                      const float* __restrict__ asr,
                                                      const float* __restrict__ adt,
                                                      float* __restrict__ ssrc,
                                                      float* __restrict__ sdst, int nN) {
  int wid = (blockIdx.x * blockDim.x + threadIdx.x) >> 6;
  int lane = threadIdx.x & 63;
  if (wid >= nN) return;
  float2 hv = *(const float2*)&h1[(size_t)wid * 128 + lane * 2];
  float2 av = *(const float2*)&asr[lane * 2];
  float2 dv = *(const float2*)&adt[lane * 2];
  float ps = hv.x * av.x + hv.y * av.y;
  float pd = hv.x * dv.x + hv.y * dv.y;
#pragma unroll
  for (int s = 1; s < 8; s <<= 1) {
    ps += __shfl_xor(ps, s);
    pd += __shfl_xor(pd, s);
  }
  if ((lane & 7) == 0) {
    ssrc[wid * 8 + (lane >> 3)] = ps;
    sdst[wid * 8 + (lane >> 3)] = pd;
  }
}

// ---------------- attention scores, layer 2: per node (1 head, 128 ch) ----------------
__global__ __launch_bounds__(256) void scores2_kernel(const float* __restrict__ h2,
                                                      const float* __restrict__ asr,
                                                      const float* __restrict__ adt,
                                                      float* __restrict__ ssrc,
                                                      float* __restrict__ sdst, int nN) {
  int wid = (blockIdx.x * blockDim.x + threadIdx.x) >> 6;
  int lane = threadIdx.x & 63;
  if (wid >= nN) return;
  float2 hv = *(const float2*)&h2[(size_t)wid * 128 + lane * 2];
  float2 av = *(const float2*)&asr[lane * 2];
  float2 dv = *(const float2*)&adt[lane * 2];
  float ps = hv.x * av.x + hv.y * av.y;
  float pd = hv.x * dv.x + hv.y * dv.y;
#pragma unroll
  for (int s = 1; s < 64; s <<= 1) {
    ps += __shfl_xor(ps, s);
    pd += __shfl_xor(pd, s);
  }
  if (lane == 0) {
    ssrc[wid] = ps;
    sdst[wid] = pd;
  }
}

// ---------------- CSR build ----------------
__global__ void hist_kernel(const int* __restrict__ ei, int* __restrict__ deg, int nE, int nN) {
  int e = blockIdx.x * blockDim.x + threadIdx.x;
  if (e >= nE + nN) return;
  int dst = (e < nE) ? ei[nE + e] : (e - nE);
  atomicAdd(&deg[dst], 1);
}

__global__ __launch_bounds__(1024) void scan_kernel(const int* __restrict__ deg,
                                                    int* __restrict__ offs, int n) {
  __shared__ int wsum[16];
  __shared__ int carry_s;
  int tid = threadIdx.x;
  int lane = tid & 63, w = tid >> 6;
  if (tid == 0) carry_s = 0;
  __syncthreads();
  for (int base = 0; base < n; base += 1024) {
    int v = (base + tid < n) ? deg[base + tid] : 0;
    int x = v;  // inclusive wave scan
#pragma unroll
    for (int s = 1; s < 64; s <<= 1) {
      int t = __shfl_up(x, s);
      if (lane >= s) x += t;
    }
    if (lane == 63) wsum[w] = x;
    __syncthreads();
    if (w == 0) {
      int wv = (lane < 16) ? wsum[lane] : 0;
      int y = wv;
#pragma unroll
      for (int s = 1; s < 16; s <<= 1) {
        int t = __shfl_up(y, s);
        if (lane >= s) y += t;
      }
      if (lane < 16) wsum[lane] = y - wv;  // exclusive wave offsets
    }
    __syncthreads();
    int c = carry_s;
    int inc = x + wsum[w];  // inclusive within chunk
    if (base + tid < n) offs[base + tid] = c + inc - v;
    __syncthreads();
    if (tid == 1023) carry_s = c + inc;
    __syncthreads();
  }
  if (tid == 0) offs[n] = carry_s;
}

__global__ void fill_kernel(const int* __restrict__ ei, const int* __restrict__ offs,
                            int* __restrict__ cursor, int* __restrict__ csr, int nE, int nN) {
  int e = blockIdx.x * blockDim.x + threadIdx.x;
  if (e >= nE + nN) return;
  int src, dst;
  if (e < nE) {
    src = ei[e];
    dst = ei[nE + e];
  } else {
    src = dst = e - nE;
  }
  int pos = atomicAdd(&cursor[dst], 1);
  csr[offs[dst] + pos] = src;
}

// ---------------- softmax denominators (no max-subtraction; scores are small) ----------------
__global__ void den1_kernel(const int* __restrict__ ei, const float* __restrict__ ssrc,
                            const float* __restrict__ sdst, float* __restrict__ den,
                            int nE, int nN) {
  int gid = blockIdx.x * blockDim.x + threadIdx.x;
  int e = gid >> 3, h = gid & 7;
  if (e >= nE + nN) return;
  int src, dst;
  if (e < nE) {
    src = ei[e];
    dst = ei[nE + e];
  } else {
    src = dst = e - nE;
  }
  float v = leaky02(ssrc[src * 8 + h] + sdst[dst * 8 + h]);
  atomicAdd(&den[dst * 8 + h], __expf(v));
}

__global__ void den2_kernel(const int* __restrict__ ei, const float* __restrict__ ssrc,
                            const float* __restrict__ sdst, float* __restrict__ den,
                            int nE, int nN) {
  int e = blockIdx.x * blockDim.x + threadIdx.x;
  if (e >= nE + nN) return;
  int src, dst;
  if (e < nE) {
    src = ei[e];
    dst = ei[nE + e];
  } else {
    src = dst = e - nE;
  }
  float v = leaky02(ssrc[src] + sdst[dst]);
  atomicAdd(&den[dst], __expf(v));
}

// ---------------- aggregation: one wave per dst node, CSR gather ----------------
__global__ __launch_bounds__(256) void agg1_kernel(const float* __restrict__ h1,
                                                   const int* __restrict__ csr,
                                                   const int* __restrict__ offs,
                                                   const float* __restrict__ ssrc,
                                                   const float* __restrict__ sdst,
                                                   const float* __restrict__ den,
                                                   const float* __restrict__ bias,
                                                   float* __restrict__ out, int nN) {
  int wid = (blockIdx.x * blockDim.x + threadIdx.x) >> 6;
  int lane = threadIdx.x & 63;
  if (wid >= nN) return;
  int c = lane * 2;
  int h = lane >> 3;
  float sd = sdst[wid * 8 + h];
  float invd = 1.0f / (den[wid * 8 + h] + 1e-16f);
  float a0 = bias[c], a1 = bias[c + 1];
  int beg = offs[wid], end = offs[wid + 1];
  for (int i = beg; i < end; ++i) {
    int src = csr[i];
    float alpha = __expf(leaky02(ssrc[src * 8 + h] + sd)) * invd;
    float2 hv = *(const float2*)&h1[(size_t)src * 128 + c];
    a0 += alpha * hv.x;
    a1 += alpha * hv.y;
  }
  *(float2*)&out[(size_t)wid * 128 + c] = make_float2(a0, a1);
}

__global__ __launch_bounds__(256) void agg2_kernel(const float* __restrict__ h2,
                                                   const int* __restrict__ csr,
                                                   const int* __restrict__ offs,
                                                   const float* __restrict__ ssrc,
                                                   const float* __restrict__ sdst,
                                                   const float* __restrict__ den,
                                                   const float* __restrict__ bias,
                                                   float* __restrict__ out, int nN) {
  int wid = (blockIdx.x * blockDim.x + threadIdx.x) >> 6;
  int lane = threadIdx.x & 63;
  if (wid >= nN) return;
  int c = lane * 2;
  float sd = sdst[wid];
  float invd = 1.0f / (den[wid] + 1e-16f);
  float a0 = bias[c], a1 = bias[c + 1];
  int beg = offs[wid], end = offs[wid + 1];
  for (int i = beg; i < end; ++i) {
    int src = csr[i];
    float alpha = __expf(leaky02(ssrc[src] + sd)) * invd;
    float2 hv = *(const float2*)&h2[(size_t)src * 128 + c];
    a0 += alpha * hv.x;
    a1 += alpha * hv.y;
  }
  *(float2*)&out[(size_t)wid * 128 + c] = make_float2(a0, a1);
}

// ---------------- column stats (sum, sumsq) for BatchNorm ----------------
__global__ __launch_bounds__(256) void stats_kernel(const float* __restrict__ X,
                                                    float* __restrict__ stats, int n) {
  __shared__ float red[256];
  int tid = threadIdx.x;
  int c = tid & 127;
  int half = tid >> 7;
  float s = 0.f, sq = 0.f;
  int rend = min((int)(blockIdx.x + 1) * 256, n);
  for (int r = (int)blockIdx.x * 256 + half; r < rend; r += 2) {
    float v = X[(size_t)r * 128 + c];
    s += v;
    sq += v * v;
  }
  red[tid] = s;
  __syncthreads();
  float s2 = (half == 0) ? s + red[tid + 128] : 0.f;
  __syncthreads();
  red[tid] = sq;
  __syncthreads();
  if (half == 0) {
    float sq2 = sq + red[tid + 128];
    atomicAdd(&stats[c], s2);
    atomicAdd(&stats[128 + c], sq2);
  }
}

// ---------------- BatchNorm (batch stats, biased var) + SELU ----------------
__global__ __launch_bounds__(256) void bnselu_kernel(const float* __restrict__ X,
                                                     const float* __restrict__ stats,
                                                     const float* __restrict__ gamma,
                                                     const float* __restrict__ beta,
                                                     float* __restrict__ Y, int n) {
  int gid = blockIdx.x * blockDim.x + threadIdx.x;
  if (gid >= n * 32) return;
  int c = (gid & 31) * 4;
  int r = gid >> 5;
  float invN = 1.0f / (float)n;
  float4 x = *(const float4*)&X[(size_t)r * 128 + c];
  float o[4];
#pragma unroll
  for (int j = 0; j < 4; ++j) {
    float xx = (j == 0) ? x.x : (j == 1) ? x.y : (j == 2) ? x.z : x.w;
    float mu = stats[c + j] * invN;
    float var = stats[128 + c + j] * invN - mu * mu;
    float rs = rsqrtf(var + 1e-5f);
    float y = gamma[c + j] * ((xx - mu) * rs) + beta[c + j];
    o[j] = y > 0.f ? SELU_SCALE * y : SELU_SCALE * SELU_ALPHA * (__expf(y) - 1.f);
  }
  *(float4*)&Y[(size_t)r * 128 + c] = make_float4(o[0], o[1], o[2], o[3]);
}

extern "C" void kernel_launch(void* const* d_in, const int* in_sizes, int n_in,
                              void* d_out, int out_size, void* d_ws, size_t ws_size,
                              hipStream_t stream) {
  const float* x   = (const float*)d_in[0];
  const int*   ei  = (const int*)d_in[1];
  // d_in[2] = edge_attr: unused (edge_dim=None)
  const float* W1  = (const float*)d_in[3];
  const float* as1 = (const float*)d_in[4];
  const float* ad1 = (const float*)d_in[5];
  const float* b1  = (const float*)d_in[6];
  const float* g1  = (const float*)d_in[7];
  const float* be1 = (const float*)d_in[8];
  const float* W2  = (const float*)d_in[9];
  const float* as2 = (const float*)d_in[10];
  const float* ad2 = (const float*)d_in[11];
  const float* b2  = (const float*)d_in[12];
  const float* g2  = (const float*)d_in[13];
  const float* be2 = (const float*)d_in[14];
  float* out = (float*)d_out;

  const int n  = in_sizes[0] / 128;   // 50000
  const int nE = in_sizes[1] / 2;     // 800000
  const int EA = nE + n;              // 850000

  float* ws = (float*)d_ws;
  size_t o = 0;
  float* A = ws + o;      o += (size_t)n * 128;   // h1 / h_bn
  float* B = ws + o;      o += (size_t)n * 128;   // out1 / h2
  float* ssrc1 = ws + o;  o += (size_t)n * 8;
  float* sdst1 = ws + o;  o += (size_t)n * 8;
  float* ssrc2 = ws + o;  o += n;
  float* sdst2 = ws + o;  o += n;
  // ---- zero region start ----
  float* zbase = ws + o;
  float* den1 = ws + o;   o += (size_t)n * 8;
  float* den2 = ws + o;   o += n;
  float* stats1 = ws + o; o += 256;
  float* stats2 = ws + o; o += 256;
  int* deg    = (int*)(ws + o); o += n;
  int* cursor = (int*)(ws + o); o += n;
  size_t zwords = (size_t)((ws + o) - zbase);
  // ---- zero region end ----
  int* offs = (int*)(ws + o); o += (size_t)n + 1;
  int* csr  = (int*)(ws + o); o += EA;

  hipMemsetAsync(zbase, 0, zwords * sizeof(float), stream);

  // CSR build (shared by both layers)
  hist_kernel<<<(EA + 255) / 256, 256, 0, stream>>>(ei, deg, nE, n);
  scan_kernel<<<1, 1024, 0, stream>>>(deg, offs, n);
  fill_kernel<<<(EA + 255) / 256, 256, 0, stream>>>(ei, offs, cursor, csr, nE, n);

  // ---- layer 1 ----
  gemm128_kernel<<<(n + 31) / 32, 256, 0, stream>>>(x, W1, A, n);
  scores1_kernel<<<(n + 3) / 4, 256, 0, stream>>>(A, as1, ad1, ssrc1, sdst1, n);
  den1_kernel<<<(EA * 8 + 255) / 256, 256, 0, stream>>>(ei, ssrc1, sdst1, den1, nE, n);
  agg1_kernel<<<(n + 3) / 4, 256, 0, stream>>>(A, csr, offs, ssrc1, sdst1, den1, b1, B, n);
  stats_kernel<<<(n + 255) / 256, 256, 0, stream>>>(B, stats1, n);
  bnselu_kernel<<<(n * 32 + 255) / 256, 256, 0, stream>>>(B, stats1, g1, be1, A, n);

  // ---- layer 2 ----
  gemm128_kernel<<<(n + 31) / 32, 256, 0, stream>>>(A, W2, B, n);
  scores2_kernel<<<(n + 3) / 4, 256, 0, stream>>>(B, as2, ad2, ssrc2, sdst2, n);
  den2_kernel<<<(EA + 255) / 256, 256, 0, stream>>>(ei, ssrc2, sdst2, den2, nE, n);
  agg2_kernel<<<(n + 3) / 4, 256, 0, stream>>>(B, csr, offs, ssrc2, sdst2, den2, b2, out, n);
  stats_kernel<<<(n + 255) / 256, 256, 0, stream>>>(out, stats2, n);
  bnselu_kernel<<<(n * 32 + 255) / 256, 256, 0, stream>>>(out, stats2, g2, be2, out, n);
}

// Round 2
// 483.111 us; speedup vs baseline: 1.3640x; 1.3640x over previous
//
#include <hip/hip_runtime.h>

#define SELU_SCALE 1.0507009873554805f
#define SELU_ALPHA 1.6732632423543772f

static __device__ __forceinline__ float leaky02(float v) {
  return v > 0.0f ? v : 0.2f * v;
}

// fp32 -> bf16 (round to nearest even), stored as ushort
static __device__ __forceinline__ ushort f2bf(float f) {
  uint b = __float_as_uint(f);
  return (ushort)((b + 0x7fffu + ((b >> 16) & 1u)) >> 16);
}
static __device__ __forceinline__ float bf2f(ushort u) {
  return __uint_as_float(((uint)u) << 16);
}

// ---------------- GEMM: Y[n,128](bf16) = X[n,128](f32) @ W[128,128](f32) ----------------
__global__ __launch_bounds__(256) void gemm128_kernel(const float* __restrict__ X,
                                                      const float* __restrict__ W,
                                                      ushort* __restrict__ Y, int n) {
  __shared__ float Ws[128][128];
  __shared__ float Xs[32][128];
  const int tid = threadIdx.x;
  {
    const float4* W4 = (const float4*)W;
    float4* S4 = (float4*)&Ws[0][0];
#pragma unroll
    for (int i = 0; i < 16; ++i) S4[i * 256 + tid] = W4[i * 256 + tid];
  }
  const int row0 = blockIdx.x * 32;
  {
    const float4* X4 = (const float4*)(X + (size_t)row0 * 128);
    float4* S4 = (float4*)&Xs[0][0];
    const int maxv = (n - row0) * 32;  // valid float4 count in this tile
#pragma unroll
    for (int i = 0; i < 4; ++i) {
      int idx = i * 256 + tid;
      float4 v = make_float4(0.f, 0.f, 0.f, 0.f);
      if (idx < maxv) v = X4[idx];
      S4[idx] = v;
    }
  }
  __syncthreads();
  const int c4 = (tid & 31) * 4;
  const int r0 = (tid >> 5) * 4;
  float acc[4][4];
#pragma unroll
  for (int i = 0; i < 4; ++i)
#pragma unroll
    for (int j = 0; j < 4; ++j) acc[i][j] = 0.f;

#pragma unroll 8
  for (int k4 = 0; k4 < 32; ++k4) {
    float4 xv[4];
#pragma unroll
    for (int i = 0; i < 4; ++i) xv[i] = *(const float4*)&Xs[r0 + i][k4 * 4];
#pragma unroll
    for (int j = 0; j < 4; ++j) {
      float4 w = *(const float4*)&Ws[k4 * 4 + j][c4];
#pragma unroll
      for (int i = 0; i < 4; ++i) {
        float xx = (j == 0) ? xv[i].x : (j == 1) ? xv[i].y : (j == 2) ? xv[i].z : xv[i].w;
        acc[i][0] += xx * w.x;
        acc[i][1] += xx * w.y;
        acc[i][2] += xx * w.z;
        acc[i][3] += xx * w.w;
      }
    }
  }
#pragma unroll
  for (int i = 0; i < 4; ++i) {
    int r = row0 + r0 + i;
    if (r < n) {
      ushort4 o;
      o.x = f2bf(acc[i][0]);
      o.y = f2bf(acc[i][1]);
      o.z = f2bf(acc[i][2]);
      o.w = f2bf(acc[i][3]);
      *(ushort4*)&Y[(size_t)r * 128 + c4] = o;
    }
  }
}

// ---------------- attention scores, layer 1: per (node, head=8) ----------------
__global__ __launch_bounds__(256) void scores1_kernel(const ushort* __restrict__ h1,
                                                      const float* __restrict__ asr,
                                                      const float* __restrict__ adt,
                                                      float* __restrict__ ssrc,
                                                      float* __restrict__ sdst, int nN) {
  int wid = (blockIdx.x * blockDim.x + threadIdx.x) >> 6;
  int lane = threadIdx.x & 63;
  if (wid >= nN) return;
  ushort2 hu = *(const ushort2*)&h1[(size_t)wid * 128 + lane * 2];
  float hx = bf2f(hu.x), hy = bf2f(hu.y);
  float2 av = *(const float2*)&asr[lane * 2];
  float2 dv = *(const float2*)&adt[lane * 2];
  float ps = hx * av.x + hy * av.y;
  float pd = hx * dv.x + hy * dv.y;
#pragma unroll
  for (int s = 1; s < 8; s <<= 1) {
    ps += __shfl_xor(ps, s);
    pd += __shfl_xor(pd, s);
  }
  if ((lane & 7) == 0) {
    ssrc[wid * 8 + (lane >> 3)] = ps;
    sdst[wid * 8 + (lane >> 3)] = pd;
  }
}

// ---------------- attention scores, layer 2: per node (1 head, 128 ch) ----------------
__global__ __launch_bounds__(256) void scores2_kernel(const ushort* __restrict__ h2,
                                                      const float* __restrict__ asr,
                                                      const float* __restrict__ adt,
                                                      float* __restrict__ ssrc,
                                                      float* __restrict__ sdst, int nN) {
  int wid = (blockIdx.x * blockDim.x + threadIdx.x) >> 6;
  int lane = threadIdx.x & 63;
  if (wid >= nN) return;
  ushort2 hu = *(const ushort2*)&h2[(size_t)wid * 128 + lane * 2];
  float hx = bf2f(hu.x), hy = bf2f(hu.y);
  float2 av = *(const float2*)&asr[lane * 2];
  float2 dv = *(const float2*)&adt[lane * 2];
  float ps = hx * av.x + hy * av.y;
  float pd = hx * dv.x + hy * dv.y;
#pragma unroll
  for (int s = 1; s < 64; s <<= 1) {
    ps += __shfl_xor(ps, s);
    pd += __shfl_xor(pd, s);
  }
  if (lane == 0) {
    ssrc[wid] = ps;
    sdst[wid] = pd;
  }
}

// ---------------- CSR build ----------------
__global__ void hist_kernel(const int* __restrict__ ei, int* __restrict__ deg, int nE, int nN) {
  int e = blockIdx.x * blockDim.x + threadIdx.x;
  if (e >= nE + nN) return;
  int dst = (e < nE) ? ei[nE + e] : (e - nE);
  atomicAdd(&deg[dst], 1);
}

__global__ __launch_bounds__(1024) void scan_kernel(const int* __restrict__ deg,
                                                    int* __restrict__ offs, int n) {
  __shared__ int wsum[16];
  __shared__ int carry_s;
  int tid = threadIdx.x;
  int lane = tid & 63, w = tid >> 6;
  if (tid == 0) carry_s = 0;
  __syncthreads();
  for (int base = 0; base < n; base += 1024) {
    int v = (base + tid < n) ? deg[base + tid] : 0;
    int x = v;  // inclusive wave scan
#pragma unroll
    for (int s = 1; s < 64; s <<= 1) {
      int t = __shfl_up(x, s);
      if (lane >= s) x += t;
    }
    if (lane == 63) wsum[w] = x;
    __syncthreads();
    if (w == 0) {
      int wv = (lane < 16) ? wsum[lane] : 0;
      int y = wv;
#pragma unroll
      for (int s = 1; s < 16; s <<= 1) {
        int t = __shfl_up(y, s);
        if (lane >= s) y += t;
      }
      if (lane < 16) wsum[lane] = y - wv;  // exclusive wave offsets
    }
    __syncthreads();
    int c = carry_s;
    int inc = x + wsum[w];  // inclusive within chunk
    if (base + tid < n) offs[base + tid] = c + inc - v;
    __syncthreads();
    if (tid == 1023) carry_s = c + inc;
    __syncthreads();
  }
  if (tid == 0) offs[n] = carry_s;
}

__global__ void fill_kernel(const int* __restrict__ ei, const int* __restrict__ offs,
                            int* __restrict__ cursor, int* __restrict__ csr, int nE, int nN) {
  int e = blockIdx.x * blockDim.x + threadIdx.x;
  if (e >= nE + nN) return;
  int src, dst;
  if (e < nE) {
    src = ei[e];
    dst = ei[nE + e];
  } else {
    src = dst = e - nE;
  }
  int pos = atomicAdd(&cursor[dst], 1);
  csr[offs[dst] + pos] = src;
}

// ---------------- aggregation (fused softmax): one wave per dst node ----------------
// out[dst,c] = (sum_e exp(leaky(ssrc[src]+sdst[dst])) * h[src,c]) / (sum_e exp(...)) + bias[c]
__global__ __launch_bounds__(256) void agg1_kernel(const ushort* __restrict__ h1,
                                                   const int* __restrict__ csr,
                                                   const int* __restrict__ offs,
                                                   const float* __restrict__ ssrc,
                                                   const float* __restrict__ sdst,
                                                   const float* __restrict__ bias,
                                                   float* __restrict__ out, int nN) {
  int wid = (blockIdx.x * blockDim.x + threadIdx.x) >> 6;
  int lane = threadIdx.x & 63;
  if (wid >= nN) return;
  int c = lane * 2;
  int h = lane >> 3;
  float sd = sdst[wid * 8 + h];
  float n0 = 0.f, n1 = 0.f, den = 0.f;
  int beg = offs[wid], end = offs[wid + 1];
  int i = beg;
  for (; i + 1 < end; i += 2) {
    int s0 = csr[i], s1 = csr[i + 1];
    float e0 = ssrc[s0 * 8 + h];
    float e1 = ssrc[s1 * 8 + h];
    ushort2 u0 = *(const ushort2*)&h1[(size_t)s0 * 128 + c];
    ushort2 u1 = *(const ushort2*)&h1[(size_t)s1 * 128 + c];
    float a0 = __expf(leaky02(e0 + sd));
    float a1 = __expf(leaky02(e1 + sd));
    n0 += a0 * bf2f(u0.x) + a1 * bf2f(u1.x);
    n1 += a0 * bf2f(u0.y) + a1 * bf2f(u1.y);
    den += a0 + a1;
  }
  if (i < end) {
    int s0 = csr[i];
    float e0 = ssrc[s0 * 8 + h];
    ushort2 u0 = *(const ushort2*)&h1[(size_t)s0 * 128 + c];
    float a0 = __expf(leaky02(e0 + sd));
    n0 += a0 * bf2f(u0.x);
    n1 += a0 * bf2f(u0.y);
    den += a0;
  }
  float invd = 1.0f / (den + 1e-16f);
  *(float2*)&out[(size_t)wid * 128 + c] =
      make_float2(n0 * invd + bias[c], n1 * invd + bias[c + 1]);
}

__global__ __launch_bounds__(256) void agg2_kernel(const ushort* __restrict__ h2,
                                                   const int* __restrict__ csr,
                                                   const int* __restrict__ offs,
                                                   const float* __restrict__ ssrc,
                                                   const float* __restrict__ sdst,
                                                   const float* __restrict__ bias,
                                                   float* __restrict__ out, int nN) {
  int wid = (blockIdx.x * blockDim.x + threadIdx.x) >> 6;
  int lane = threadIdx.x & 63;
  if (wid >= nN) return;
  int c = lane * 2;
  float sd = sdst[wid];
  float n0 = 0.f, n1 = 0.f, den = 0.f;
  int beg = offs[wid], end = offs[wid + 1];
  int i = beg;
  for (; i + 1 < end; i += 2) {
    int s0 = csr[i], s1 = csr[i + 1];
    float e0 = ssrc[s0];
    float e1 = ssrc[s1];
    ushort2 u0 = *(const ushort2*)&h2[(size_t)s0 * 128 + c];
    ushort2 u1 = *(const ushort2*)&h2[(size_t)s1 * 128 + c];
    float a0 = __expf(leaky02(e0 + sd));
    float a1 = __expf(leaky02(e1 + sd));
    n0 += a0 * bf2f(u0.x) + a1 * bf2f(u1.x);
    n1 += a0 * bf2f(u0.y) + a1 * bf2f(u1.y);
    den += a0 + a1;
  }
  if (i < end) {
    int s0 = csr[i];
    float e0 = ssrc[s0];
    ushort2 u0 = *(const ushort2*)&h2[(size_t)s0 * 128 + c];
    float a0 = __expf(leaky02(e0 + sd));
    n0 += a0 * bf2f(u0.x);
    n1 += a0 * bf2f(u0.y);
    den += a0;
  }
  float invd = 1.0f / (den + 1e-16f);
  *(float2*)&out[(size_t)wid * 128 + c] =
      make_float2(n0 * invd + bias[c], n1 * invd + bias[c + 1]);
}

// ---------------- column stats (sum, sumsq) for BatchNorm ----------------
__global__ __launch_bounds__(256) void stats_kernel(const float* __restrict__ X,
                                                    float* __restrict__ stats, int n) {
  __shared__ float red[256];
  int tid = threadIdx.x;
  int c = tid & 127;
  int half = tid >> 7;
  float s = 0.f, sq = 0.f;
  int rend = min((int)(blockIdx.x + 1) * 256, n);
  for (int r = (int)blockIdx.x * 256 + half; r < rend; r += 2) {
    float v = X[(size_t)r * 128 + c];
    s += v;
    sq += v * v;
  }
  red[tid] = s;
  __syncthreads();
  float s2 = (half == 0) ? s + red[tid + 128] : 0.f;
  __syncthreads();
  red[tid] = sq;
  __syncthreads();
  if (half == 0) {
    float sq2 = sq + red[tid + 128];
    atomicAdd(&stats[c], s2);
    atomicAdd(&stats[128 + c], sq2);
  }
}

// ---------------- BatchNorm (batch stats, biased var) + SELU ----------------
__global__ __launch_bounds__(256) void bnselu_kernel(const float* __restrict__ X,
                                                     const float* __restrict__ stats,
                                                     const float* __restrict__ gamma,
                                                     const float* __restrict__ beta,
                                                     float* __restrict__ Y, int n) {
  int gid = blockIdx.x * blockDim.x + threadIdx.x;
  if (gid >= n * 32) return;
  int c = (gid & 31) * 4;
  int r = gid >> 5;
  float invN = 1.0f / (float)n;
  float4 x = *(const float4*)&X[(size_t)r * 128 + c];
  float o[4];
#pragma unroll
  for (int j = 0; j < 4; ++j) {
    float xx = (j == 0) ? x.x : (j == 1) ? x.y : (j == 2) ? x.z : x.w;
    float mu = stats[c + j] * invN;
    float var = stats[128 + c + j] * invN - mu * mu;
    float rs = rsqrtf(var + 1e-5f);
    float y = gamma[c + j] * ((xx - mu) * rs) + beta[c + j];
    o[j] = y > 0.f ? SELU_SCALE * y : SELU_SCALE * SELU_ALPHA * (__expf(y) - 1.f);
  }
  *(float4*)&Y[(size_t)r * 128 + c] = make_float4(o[0], o[1], o[2], o[3]);
}

extern "C" void kernel_launch(void* const* d_in, const int* in_sizes, int n_in,
                              void* d_out, int out_size, void* d_ws, size_t ws_size,
                              hipStream_t stream) {
  const float* x   = (const float*)d_in[0];
  const int*   ei  = (const int*)d_in[1];
  // d_in[2] = edge_attr: unused (edge_dim=None)
  const float* W1  = (const float*)d_in[3];
  const float* as1 = (const float*)d_in[4];
  const float* ad1 = (const float*)d_in[5];
  const float* b1  = (const float*)d_in[6];
  const float* g1  = (const float*)d_in[7];
  const float* be1 = (const float*)d_in[8];
  const float* W2  = (const float*)d_in[9];
  const float* as2 = (const float*)d_in[10];
  const float* ad2 = (const float*)d_in[11];
  const float* b2  = (const float*)d_in[12];
  const float* g2  = (const float*)d_in[13];
  const float* be2 = (const float*)d_in[14];
  float* out = (float*)d_out;

  const int n  = in_sizes[0] / 128;   // 50000
  const int nE = in_sizes[1] / 2;     // 800000
  const int EA = nE + n;              // 850000

  float* ws = (float*)d_ws;
  size_t o = 0;
  float* Bf = ws + o;     o += (size_t)n * 128;   // fp32: agg output / BN input
  float* Af = ws + o;     o += (size_t)n * 128;   // fp32: BN output (GEMM2 input)
  ushort* H = (ushort*)(ws + o); o += (size_t)n * 64;  // bf16 h (gather table, reused)
  float* ssrc1 = ws + o;  o += (size_t)n * 8;
  float* sdst1 = ws + o;  o += (size_t)n * 8;
  float* ssrc2 = ws + o;  o += n;
  float* sdst2 = ws + o;  o += n;
  // ---- zero region start ----
  float* zbase = ws + o;
  float* stats1 = ws + o; o += 256;
  float* stats2 = ws + o; o += 256;
  int* deg    = (int*)(ws + o); o += n;
  int* cursor = (int*)(ws + o); o += n;
  size_t zwords = (size_t)((ws + o) - zbase);
  // ---- zero region end ----
  int* offs = (int*)(ws + o); o += (size_t)n + 1;
  int* csr  = (int*)(ws + o); o += EA;

  hipMemsetAsync(zbase, 0, zwords * sizeof(float), stream);

  // CSR build (shared by both layers)
  hist_kernel<<<(EA + 255) / 256, 256, 0, stream>>>(ei, deg, nE, n);
  scan_kernel<<<1, 1024, 0, stream>>>(deg, offs, n);
  fill_kernel<<<(EA + 255) / 256, 256, 0, stream>>>(ei, offs, cursor, csr, nE, n);

  // ---- layer 1 ----
  gemm128_kernel<<<(n + 31) / 32, 256, 0, stream>>>(x, W1, H, n);
  scores1_kernel<<<(n + 3) / 4, 256, 0, stream>>>(H, as1, ad1, ssrc1, sdst1, n);
  agg1_kernel<<<(n + 3) / 4, 256, 0, stream>>>(H, csr, offs, ssrc1, sdst1, b1, Bf, n);
  stats_kernel<<<(n + 255) / 256, 256, 0, stream>>>(Bf, stats1, n);
  bnselu_kernel<<<(n * 32 + 255) / 256, 256, 0, stream>>>(Bf, stats1, g1, be1, Af, n);

  // ---- layer 2 ----
  gemm128_kernel<<<(n + 31) / 32, 256, 0, stream>>>(Af, W2, H, n);
  scores2_kernel<<<(n + 3) / 4, 256, 0, stream>>>(H, as2, ad2, ssrc2, sdst2, n);
  agg2_kernel<<<(n + 3) / 4, 256, 0, stream>>>(H, csr, offs, ssrc2, sdst2, b2, out, n);
  stats_kernel<<<(n + 255) / 256, 256, 0, stream>>>(out, stats2, n);
  bnselu_kernel<<<(n * 32 + 255) / 256, 256, 0, stream>>>(out, stats2, g2, be2, out, n);
}

// Round 3
// 372.680 us; speedup vs baseline: 1.7682x; 1.2963x over previous
//
#include <hip/hip_runtime.h>

#define SELU_SCALE 1.0507009873554805f
#define SELU_ALPHA 1.6732632423543772f

static __device__ __forceinline__ float leaky02(float v) {
  return v > 0.0f ? v : 0.2f * v;
}

// fp32 -> bf16 (round to nearest even), stored as ushort
static __device__ __forceinline__ ushort f2bf(float f) {
  uint b = __float_as_uint(f);
  return (ushort)((b + 0x7fffu + ((b >> 16) & 1u)) >> 16);
}
static __device__ __forceinline__ float bf2f(ushort u) {
  return __uint_as_float(((uint)u) << 16);
}

static __device__ __forceinline__ float selu_f(float y) {
  return y > 0.f ? SELU_SCALE * y : SELU_SCALE * SELU_ALPHA * (__expf(y) - 1.f);
}

// ---------------- GEMM: Y[n,128](bf16) = X[n,128](f32) @ W[128,128](f32) ----------------
// If stats != nullptr, applies BatchNorm(batch stats)+SELU to X on load.
template <bool BN>
__global__ __launch_bounds__(256) void gemm128_kernel(const float* __restrict__ X,
                                                      const float* __restrict__ W,
                                                      ushort* __restrict__ Y, int n,
                                                      const float* __restrict__ stats,
                                                      const float* __restrict__ gamma,
                                                      const float* __restrict__ beta) {
  __shared__ float Ws[128][128];
  __shared__ float Xs[32][128];
  const int tid = threadIdx.x;
  {
    const float4* W4 = (const float4*)W;
    float4* S4 = (float4*)&Ws[0][0];
#pragma unroll
    for (int i = 0; i < 16; ++i) S4[i * 256 + tid] = W4[i * 256 + tid];
  }
  const int row0 = blockIdx.x * 32;
  const float invN = 1.0f / (float)n;
  {
    const float4* X4 = (const float4*)(X + (size_t)row0 * 128);
    float4* S4 = (float4*)&Xs[0][0];
    const int maxv = (n - row0) * 32;  // valid float4 count in this tile
#pragma unroll
    for (int i = 0; i < 4; ++i) {
      int idx = i * 256 + tid;
      float4 v = make_float4(0.f, 0.f, 0.f, 0.f);
      if (idx < maxv) v = X4[idx];
      if (BN) {
        int c = (idx & 31) * 4;
        float vv[4] = {v.x, v.y, v.z, v.w};
#pragma unroll
        for (int j = 0; j < 4; ++j) {
          float mu = stats[c + j] * invN;
          float var = stats[128 + c + j] * invN - mu * mu;
          float rs = rsqrtf(var + 1e-5f);
          vv[j] = selu_f(gamma[c + j] * ((vv[j] - mu) * rs) + beta[c + j]);
        }
        v = make_float4(vv[0], vv[1], vv[2], vv[3]);
      }
      S4[idx] = v;
    }
  }
  __syncthreads();
  const int c4 = (tid & 31) * 4;
  const int r0 = (tid >> 5) * 4;
  float acc[4][4];
#pragma unroll
  for (int i = 0; i < 4; ++i)
#pragma unroll
    for (int j = 0; j < 4; ++j) acc[i][j] = 0.f;

#pragma unroll 8
  for (int k4 = 0; k4 < 32; ++k4) {
    float4 xv[4];
#pragma unroll
    for (int i = 0; i < 4; ++i) xv[i] = *(const float4*)&Xs[r0 + i][k4 * 4];
#pragma unroll
    for (int j = 0; j < 4; ++j) {
      float4 w = *(const float4*)&Ws[k4 * 4 + j][c4];
#pragma unroll
      for (int i = 0; i < 4; ++i) {
        float xx = (j == 0) ? xv[i].x : (j == 1) ? xv[i].y : (j == 2) ? xv[i].z : xv[i].w;
        acc[i][0] += xx * w.x;
        acc[i][1] += xx * w.y;
        acc[i][2] += xx * w.z;
        acc[i][3] += xx * w.w;
      }
    }
  }
#pragma unroll
  for (int i = 0; i < 4; ++i) {
    int r = row0 + r0 + i;
    if (r < n) {
      ushort4 o;
      o.x = f2bf(acc[i][0]);
      o.y = f2bf(acc[i][1]);
      o.z = f2bf(acc[i][2]);
      o.w = f2bf(acc[i][3]);
      *(ushort4*)&Y[(size_t)r * 128 + c4] = o;
    }
  }
}

// ---------------- attention scores, layer 1: per (node, head=8) ----------------
__global__ __launch_bounds__(256) void scores1_kernel(const ushort* __restrict__ h1,
                                                      const float* __restrict__ asr,
                                                      const float* __restrict__ adt,
                                                      float* __restrict__ ssrc,
                                                      float* __restrict__ sdst, int nN) {
  int wid = (blockIdx.x * blockDim.x + threadIdx.x) >> 6;
  int lane = threadIdx.x & 63;
  if (wid >= nN) return;
  ushort2 hu = *(const ushort2*)&h1[(size_t)wid * 128 + lane * 2];
  float hx = bf2f(hu.x), hy = bf2f(hu.y);
  float2 av = *(const float2*)&asr[lane * 2];
  float2 dv = *(const float2*)&adt[lane * 2];
  float ps = hx * av.x + hy * av.y;
  float pd = hx * dv.x + hy * dv.y;
#pragma unroll
  for (int s = 1; s < 8; s <<= 1) {
    ps += __shfl_xor(ps, s);
    pd += __shfl_xor(pd, s);
  }
  if ((lane & 7) == 0) {
    ssrc[wid * 8 + (lane >> 3)] = ps;
    sdst[wid * 8 + (lane >> 3)] = pd;
  }
}

// ---------------- attention scores, layer 2: per node (1 head, 128 ch) ----------------
__global__ __launch_bounds__(256) void scores2_kernel(const ushort* __restrict__ h2,
                                                      const float* __restrict__ asr,
                                                      const float* __restrict__ adt,
                                                      float* __restrict__ ssrc,
                                                      float* __restrict__ sdst, int nN) {
  int wid = (blockIdx.x * blockDim.x + threadIdx.x) >> 6;
  int lane = threadIdx.x & 63;
  if (wid >= nN) return;
  ushort2 hu = *(const ushort2*)&h2[(size_t)wid * 128 + lane * 2];
  float hx = bf2f(hu.x), hy = bf2f(hu.y);
  float2 av = *(const float2*)&asr[lane * 2];
  float2 dv = *(const float2*)&adt[lane * 2];
  float ps = hx * av.x + hy * av.y;
  float pd = hx * dv.x + hy * dv.y;
#pragma unroll
  for (int s = 1; s < 64; s <<= 1) {
    ps += __shfl_xor(ps, s);
    pd += __shfl_xor(pd, s);
  }
  if (lane == 0) {
    ssrc[wid] = ps;
    sdst[wid] = pd;
  }
}

// ---------------- CSR build ----------------
__global__ void hist_kernel(const int* __restrict__ ei, int* __restrict__ deg, int nE, int nN) {
  int e = blockIdx.x * blockDim.x + threadIdx.x;
  if (e >= nE + nN) return;
  int dst = (e < nE) ? ei[nE + e] : (e - nE);
  atomicAdd(&deg[dst], 1);
}

// hierarchical exclusive scan over deg[n] -> offs[n], offs[n]=total
// phase 1: per-block (1024-elem chunk) sums
__global__ __launch_bounds__(256) void scan1_kernel(const int* __restrict__ deg,
                                                    int* __restrict__ bsum, int n) {
  __shared__ int red[4];
  int b = blockIdx.x, tid = threadIdx.x;
  int lane = tid & 63, w = tid >> 6;
  int base = b * 1024 + tid * 4;
  int s = 0;
#pragma unroll
  for (int j = 0; j < 4; ++j) {
    int idx = base + j;
    if (idx < n) s += deg[idx];
  }
#pragma unroll
  for (int sh = 1; sh < 64; sh <<= 1) s += __shfl_xor(s, sh);
  if (lane == 0) red[w] = s;
  __syncthreads();
  if (tid == 0) bsum[b] = red[0] + red[1] + red[2] + red[3];
}

// phase 2: exclusive scan of bsum[nb] (single wave, serial-carry over 64-chunks), writes offs[n]=total
__global__ __launch_bounds__(64) void scan2_kernel(int* __restrict__ bsum, int* __restrict__ offs,
                                                   int nb, int n) {
  int lane = threadIdx.x;
  int carry = 0;
  for (int base = 0; base < nb; base += 64) {
    int v = (base + lane < nb) ? bsum[base + lane] : 0;
    int x = v;
#pragma unroll
    for (int s = 1; s < 64; s <<= 1) {
      int t = __shfl_up(x, s);
      if (lane >= s) x += t;
    }
    if (base + lane < nb) bsum[base + lane] = carry + x - v;  // exclusive
    carry += __shfl(x, 63);
  }
  if (lane == 0) offs[n] = carry;
}

// phase 3: per-block re-scan with block offset
__global__ __launch_bounds__(256) void scan3_kernel(const int* __restrict__ deg,
                                                    const int* __restrict__ bsum,
                                                    int* __restrict__ offs, int n) {
  __shared__ int wsum[4];
  int b = blockIdx.x, tid = threadIdx.x;
  int lane = tid & 63, w = tid >> 6;
  int base = b * 1024 + tid * 4;
  int v[4];
  int t = 0;
#pragma unroll
  for (int j = 0; j < 4; ++j) {
    int idx = base + j;
    v[j] = (idx < n) ? deg[idx] : 0;
    t += v[j];
  }
  int x = t;
#pragma unroll
  for (int s = 1; s < 64; s <<= 1) {
    int tt = __shfl_up(x, s);
    if (lane >= s) x += tt;
  }
  if (lane == 63) wsum[w] = x;
  __syncthreads();
  int woff = 0;
#pragma unroll
  for (int ww = 0; ww < 4; ++ww)
    if (ww < w) woff += wsum[ww];
  int off = bsum[b] + woff + x - t;  // exclusive prefix for this thread's first elem
#pragma unroll
  for (int j = 0; j < 4; ++j) {
    int idx = base + j;
    if (idx < n) offs[idx] = off;
    off += v[j];
  }
}

__global__ void fill_kernel(const int* __restrict__ ei, const int* __restrict__ offs,
                            int* __restrict__ cursor, int* __restrict__ csr, int nE, int nN) {
  int e = blockIdx.x * blockDim.x + threadIdx.x;
  if (e >= nE + nN) return;
  int src, dst;
  if (e < nE) {
    src = ei[e];
    dst = ei[nE + e];
  } else {
    src = dst = e - nE;
  }
  int pos = atomicAdd(&cursor[dst], 1);
  csr[offs[dst] + pos] = src;
}

// ---------------- aggregation (fused softmax): one wave per dst node ----------------
__global__ __launch_bounds__(256) void agg1_kernel(const ushort* __restrict__ h1,
                                                   const int* __restrict__ csr,
                                                   const int* __restrict__ offs,
                                                   const float* __restrict__ ssrc,
                                                   const float* __restrict__ sdst,
                                                   const float* __restrict__ bias,
                                                   float* __restrict__ out, int nN) {
  int wid = (blockIdx.x * blockDim.x + threadIdx.x) >> 6;
  int lane = threadIdx.x & 63;
  if (wid >= nN) return;
  int c = lane * 2;
  int h = lane >> 3;
  float sd = sdst[wid * 8 + h];
  float n0 = 0.f, n1 = 0.f, den = 0.f;
  int beg = offs[wid], end = offs[wid + 1];
  int i = beg;
  for (; i + 3 < end; i += 4) {
    int s0 = csr[i], s1 = csr[i + 1], s2 = csr[i + 2], s3 = csr[i + 3];
    float e0 = ssrc[s0 * 8 + h];
    float e1 = ssrc[s1 * 8 + h];
    float e2 = ssrc[s2 * 8 + h];
    float e3 = ssrc[s3 * 8 + h];
    ushort2 u0 = *(const ushort2*)&h1[(size_t)s0 * 128 + c];
    ushort2 u1 = *(const ushort2*)&h1[(size_t)s1 * 128 + c];
    ushort2 u2 = *(const ushort2*)&h1[(size_t)s2 * 128 + c];
    ushort2 u3 = *(const ushort2*)&h1[(size_t)s3 * 128 + c];
    float a0 = __expf(leaky02(e0 + sd));
    float a1 = __expf(leaky02(e1 + sd));
    float a2 = __expf(leaky02(e2 + sd));
    float a3 = __expf(leaky02(e3 + sd));
    n0 += a0 * bf2f(u0.x) + a1 * bf2f(u1.x) + a2 * bf2f(u2.x) + a3 * bf2f(u3.x);
    n1 += a0 * bf2f(u0.y) + a1 * bf2f(u1.y) + a2 * bf2f(u2.y) + a3 * bf2f(u3.y);
    den += (a0 + a1) + (a2 + a3);
  }
  for (; i < end; ++i) {
    int s0 = csr[i];
    float e0 = ssrc[s0 * 8 + h];
    ushort2 u0 = *(const ushort2*)&h1[(size_t)s0 * 128 + c];
    float a0 = __expf(leaky02(e0 + sd));
    n0 += a0 * bf2f(u0.x);
    n1 += a0 * bf2f(u0.y);
    den += a0;
  }
  float invd = 1.0f / (den + 1e-16f);
  *(float2*)&out[(size_t)wid * 128 + c] =
      make_float2(n0 * invd + bias[c], n1 * invd + bias[c + 1]);
}

__global__ __launch_bounds__(256) void agg2_kernel(const ushort* __restrict__ h2,
                                                   const int* __restrict__ csr,
                                                   const int* __restrict__ offs,
                                                   const float* __restrict__ ssrc,
                                                   const float* __restrict__ sdst,
                                                   const float* __restrict__ bias,
                                                   float* __restrict__ out, int nN) {
  int wid = (blockIdx.x * blockDim.x + threadIdx.x) >> 6;
  int lane = threadIdx.x & 63;
  if (wid >= nN) return;
  int c = lane * 2;
  float sd = sdst[wid];
  float n0 = 0.f, n1 = 0.f, den = 0.f;
  int beg = offs[wid], end = offs[wid + 1];
  int i = beg;
  for (; i + 3 < end; i += 4) {
    int s0 = csr[i], s1 = csr[i + 1], s2 = csr[i + 2], s3 = csr[i + 3];
    float e0 = ssrc[s0];
    float e1 = ssrc[s1];
    float e2 = ssrc[s2];
    float e3 = ssrc[s3];
    ushort2 u0 = *(const ushort2*)&h2[(size_t)s0 * 128 + c];
    ushort2 u1 = *(const ushort2*)&h2[(size_t)s1 * 128 + c];
    ushort2 u2 = *(const ushort2*)&h2[(size_t)s2 * 128 + c];
    ushort2 u3 = *(const ushort2*)&h2[(size_t)s3 * 128 + c];
    float a0 = __expf(leaky02(e0 + sd));
    float a1 = __expf(leaky02(e1 + sd));
    float a2 = __expf(leaky02(e2 + sd));
    float a3 = __expf(leaky02(e3 + sd));
    n0 += a0 * bf2f(u0.x) + a1 * bf2f(u1.x) + a2 * bf2f(u2.x) + a3 * bf2f(u3.x);
    n1 += a0 * bf2f(u0.y) + a1 * bf2f(u1.y) + a2 * bf2f(u2.y) + a3 * bf2f(u3.y);
    den += (a0 + a1) + (a2 + a3);
  }
  for (; i < end; ++i) {
    int s0 = csr[i];
    float e0 = ssrc[s0];
    ushort2 u0 = *(const ushort2*)&h2[(size_t)s0 * 128 + c];
    float a0 = __expf(leaky02(e0 + sd));
    n0 += a0 * bf2f(u0.x);
    n1 += a0 * bf2f(u0.y);
    den += a0;
  }
  float invd = 1.0f / (den + 1e-16f);
  *(float2*)&out[(size_t)wid * 128 + c] =
      make_float2(n0 * invd + bias[c], n1 * invd + bias[c + 1]);
}

// ---------------- column stats (sum, sumsq) for BatchNorm: 64 rows/block ----------------
__global__ __launch_bounds__(256) void stats_kernel(const float* __restrict__ X,
                                                    float* __restrict__ stats, int n) {
  __shared__ float red[256];
  int tid = threadIdx.x;
  int c = tid & 127;
  int half = tid >> 7;
  float s = 0.f, sq = 0.f;
  int rbeg = (int)blockIdx.x * 64 + half;
  int rend = min((int)(blockIdx.x + 1) * 64, n);
#pragma unroll 4
  for (int r = rbeg; r < rend; r += 2) {
    float v = X[(size_t)r * 128 + c];
    s += v;
    sq += v * v;
  }
  red[tid] = s;
  __syncthreads();
  float s2 = (half == 0) ? s + red[tid + 128] : 0.f;
  __syncthreads();
  red[tid] = sq;
  __syncthreads();
  if (half == 0) {
    float sq2 = sq + red[tid + 128];
    atomicAdd(&stats[c], s2);
    atomicAdd(&stats[128 + c], sq2);
  }
}

// ---------------- BatchNorm (batch stats, biased var) + SELU ----------------
__global__ __launch_bounds__(256) void bnselu_kernel(const float* __restrict__ X,
                                                     const float* __restrict__ stats,
                                                     const float* __restrict__ gamma,
                                                     const float* __restrict__ beta,
                                                     float* __restrict__ Y, int n) {
  int gid = blockIdx.x * blockDim.x + threadIdx.x;
  if (gid >= n * 32) return;
  int c = (gid & 31) * 4;
  int r = gid >> 5;
  float invN = 1.0f / (float)n;
  float4 x = *(const float4*)&X[(size_t)r * 128 + c];
  float o[4];
#pragma unroll
  for (int j = 0; j < 4; ++j) {
    float xx = (j == 0) ? x.x : (j == 1) ? x.y : (j == 2) ? x.z : x.w;
    float mu = stats[c + j] * invN;
    float var = stats[128 + c + j] * invN - mu * mu;
    float rs = rsqrtf(var + 1e-5f);
    float y = gamma[c + j] * ((xx - mu) * rs) + beta[c + j];
    o[j] = selu_f(y);
  }
  *(float4*)&Y[(size_t)r * 128 + c] = make_float4(o[0], o[1], o[2], o[3]);
}

extern "C" void kernel_launch(void* const* d_in, const int* in_sizes, int n_in,
                              void* d_out, int out_size, void* d_ws, size_t ws_size,
                              hipStream_t stream) {
  const float* x   = (const float*)d_in[0];
  const int*   ei  = (const int*)d_in[1];
  // d_in[2] = edge_attr: unused (edge_dim=None)
  const float* W1  = (const float*)d_in[3];
  const float* as1 = (const float*)d_in[4];
  const float* ad1 = (const float*)d_in[5];
  const float* b1  = (const float*)d_in[6];
  const float* g1  = (const float*)d_in[7];
  const float* be1 = (const float*)d_in[8];
  const float* W2  = (const float*)d_in[9];
  const float* as2 = (const float*)d_in[10];
  const float* ad2 = (const float*)d_in[11];
  const float* b2  = (const float*)d_in[12];
  const float* g2  = (const float*)d_in[13];
  const float* be2 = (const float*)d_in[14];
  float* out = (float*)d_out;

  const int n  = in_sizes[0] / 128;   // 50000
  const int nE = in_sizes[1] / 2;     // 800000
  const int EA = nE + n;              // 850000
  const int nb = (n + 1023) / 1024;   // scan chunks

  float* ws = (float*)d_ws;
  size_t o = 0;
  float* Bf = ws + o;     o += (size_t)n * 128;   // fp32: agg output / BN input
  ushort* H = (ushort*)(ws + o); o += (size_t)n * 64;  // bf16 h (gather table, reused)
  float* ssrc1 = ws + o;  o += (size_t)n * 8;
  float* sdst1 = ws + o;  o += (size_t)n * 8;
  float* ssrc2 = ws + o;  o += n;
  float* sdst2 = ws + o;  o += n;
  // ---- zero region start ----
  float* zbase = ws + o;
  float* stats1 = ws + o; o += 256;
  float* stats2 = ws + o; o += 256;
  int* deg    = (int*)(ws + o); o += n;
  int* cursor = (int*)(ws + o); o += n;
  size_t zwords = (size_t)((ws + o) - zbase);
  // ---- zero region end ----
  int* offs = (int*)(ws + o); o += (size_t)n + 1;
  int* csr  = (int*)(ws + o); o += EA;
  int* bsum = (int*)(ws + o); o += nb;

  hipMemsetAsync(zbase, 0, zwords * sizeof(float), stream);

  // CSR build (shared by both layers)
  hist_kernel<<<(EA + 255) / 256, 256, 0, stream>>>(ei, deg, nE, n);
  scan1_kernel<<<nb, 256, 0, stream>>>(deg, bsum, n);
  scan2_kernel<<<1, 64, 0, stream>>>(bsum, offs, nb, n);
  scan3_kernel<<<nb, 256, 0, stream>>>(deg, bsum, offs, n);
  fill_kernel<<<(EA + 255) / 256, 256, 0, stream>>>(ei, offs, cursor, csr, nE, n);

  // ---- layer 1 ----
  gemm128_kernel<false><<<(n + 31) / 32, 256, 0, stream>>>(x, W1, H, n, nullptr, nullptr, nullptr);
  scores1_kernel<<<(n + 3) / 4, 256, 0, stream>>>(H, as1, ad1, ssrc1, sdst1, n);
  agg1_kernel<<<(n + 3) / 4, 256, 0, stream>>>(H, csr, offs, ssrc1, sdst1, b1, Bf, n);
  stats_kernel<<<(n + 63) / 64, 256, 0, stream>>>(Bf, stats1, n);

  // ---- layer 2 (BN+SELU of layer 1 fused into GEMM2's X load) ----
  gemm128_kernel<true><<<(n + 31) / 32, 256, 0, stream>>>(Bf, W2, H, n, stats1, g1, be1);
  scores2_kernel<<<(n + 3) / 4, 256, 0, stream>>>(H, as2, ad2, ssrc2, sdst2, n);
  agg2_kernel<<<(n + 3) / 4, 256, 0, stream>>>(H, csr, offs, ssrc2, sdst2, b2, out, n);
  stats_kernel<<<(n + 63) / 64, 256, 0, stream>>>(out, stats2, n);
  bnselu_kernel<<<(n * 32 + 255) / 256, 256, 0, stream>>>(out, stats2, g2, be2, out, n);
}

// Round 5
// 295.820 us; speedup vs baseline: 2.2277x; 1.2598x over previous
//
#include <hip/hip_runtime.h>

#define SELU_SCALE 1.0507009873554805f
#define SELU_ALPHA 1.6732632423543772f

typedef __attribute__((ext_vector_type(8))) short short8;
typedef __attribute__((ext_vector_type(4))) float f32x4;

static __device__ __forceinline__ float leaky02(float v) {
  return v > 0.0f ? v : 0.2f * v;
}

// fp32 -> bf16 (round to nearest even), stored as ushort
static __device__ __forceinline__ ushort f2bf(float f) {
  uint b = __float_as_uint(f);
  return (ushort)((b + 0x7fffu + ((b >> 16) & 1u)) >> 16);
}
static __device__ __forceinline__ float bf2f(ushort u) {
  return __uint_as_float(((uint)u) << 16);
}

static __device__ __forceinline__ float selu_f(float y) {
  return y > 0.f ? SELU_SCALE * y : SELU_SCALE * SELU_ALPHA * (__expf(y) - 1.f);
}

// ---------------- W pack: W[128][128] f32 row-major -> MFMA A-fragment order (bf16) ------
// flat t = (((ct*4+kt)*4+g)*16+i)*8+b  -> bits: b[0:2], i[3:6], g[7:8], kt[9:10], ct[11:13]
// Wp[t] = bf16( W[(kt*32+g*8+b)*128 + ct*16+i] )
__global__ __launch_bounds__(256) void pack_kernel(const float* __restrict__ W1,
                                                   const float* __restrict__ W2,
                                                   ushort* __restrict__ Wp1,
                                                   ushort* __restrict__ Wp2) {
  int idx = blockIdx.x * 256 + threadIdx.x;  // 0..32767
  const float* W = (idx < 16384) ? W1 : W2;
  ushort* Wp = (idx < 16384) ? Wp1 : Wp2;
  int t = idx & 16383;
  int b = t & 7, i = (t >> 3) & 15, g = (t >> 7) & 3, kt = (t >> 9) & 3, ct = t >> 11;
  int k = kt * 32 + g * 8 + b, col = ct * 16 + i;
  Wp[t] = f2bf(W[k * 128 + col]);
}

// ---------------- MFMA GEMM + fused scores (+ optional fused BN+SELU on X load) ---------
// Y[n,128](bf16) = act(X[n,128] f32) @ W ; ssrc/sdst from f32 accumulators.
// Lane l: row = row0 + (l&15); acc[ct][r] = Y[row][ct*16 + (l>>4)*4 + r].
template <int HEADS, bool BN>
__global__ __launch_bounds__(256) void gemm_mfma_kernel(
    const float* __restrict__ X, const ushort* __restrict__ Wp, ushort* __restrict__ H,
    const float* __restrict__ asr, const float* __restrict__ adt,
    float* __restrict__ ssrc, float* __restrict__ sdst, int n,
    const float* __restrict__ stats, const float* __restrict__ gamma,
    const float* __restrict__ beta) {
  __shared__ float sc[128], sh[128];
  if (BN) {
    int t = threadIdx.x;
    if (t < 128) {
      float invN = 1.0f / (float)n;
      float mu = stats[t] * invN;
      float var = stats[128 + t] * invN - mu * mu;
      float rs = rsqrtf(var + 1e-5f);
      float s = gamma[t] * rs;
      sc[t] = s;
      sh[t] = beta[t] - s * mu;
    }
    __syncthreads();
  }
  const int tid = threadIdx.x;
  const int w = tid >> 6, l = tid & 63;
  const int lj = l & 15, lg = l >> 4;
  const int row = blockIdx.x * 64 + w * 16 + lj;
  const bool rowok = row < n;
  const float* xrow = X + (size_t)row * 128;

  f32x4 acc[8];
#pragma unroll
  for (int ct = 0; ct < 8; ++ct) acc[ct] = (f32x4){0.f, 0.f, 0.f, 0.f};

#pragma unroll
  for (int kt = 0; kt < 4; ++kt) {
    const int k0 = kt * 32 + lg * 8;
    float4 xa = make_float4(0.f, 0.f, 0.f, 0.f), xb = xa;
    if (rowok) {
      xa = *(const float4*)(xrow + k0);
      xb = *(const float4*)(xrow + k0 + 4);
    }
    float xv[8] = {xa.x, xa.y, xa.z, xa.w, xb.x, xb.y, xb.z, xb.w};
    if (BN) {
#pragma unroll
      for (int b = 0; b < 8; ++b) xv[b] = selu_f(xv[b] * sc[k0 + b] + sh[k0 + b]);
    }
    short8 bx;
#pragma unroll
    for (int b = 0; b < 8; ++b) bx[b] = (short)f2bf(xv[b]);
#pragma unroll
    for (int ct = 0; ct < 8; ++ct) {
      short8 af = *(const short8*)(Wp + ((((ct * 4 + kt) * 4 + lg) * 16 + lj) << 3));
      acc[ct] = __builtin_amdgcn_mfma_f32_16x16x32_bf16(af, bx, acc[ct], 0, 0, 0);
    }
  }

  // ---- H store: per ct, 4 consecutive bf16 cols ----
  if (rowok) {
#pragma unroll
    for (int ct = 0; ct < 8; ++ct) {
      ushort4 h4;
      h4.x = f2bf(acc[ct][0]);
      h4.y = f2bf(acc[ct][1]);
      h4.z = f2bf(acc[ct][2]);
      h4.w = f2bf(acc[ct][3]);
      *(ushort4*)&H[(size_t)row * 128 + ct * 16 + lg * 4] = h4;
    }
  }

  // ---- fused attention scores ----
  if (HEADS == 8) {
    float ps[8], pd[8];
#pragma unroll
    for (int ct = 0; ct < 8; ++ct) {
      float4 av = *(const float4*)&asr[ct * 16 + lg * 4];
      float4 dv = *(const float4*)&adt[ct * 16 + lg * 4];
      ps[ct] = acc[ct][0] * av.x + acc[ct][1] * av.y + acc[ct][2] * av.z + acc[ct][3] * av.w;
      pd[ct] = acc[ct][0] * dv.x + acc[ct][1] * dv.y + acc[ct][2] * dv.z + acc[ct][3] * dv.w;
      ps[ct] += __shfl_xor(ps[ct], 16);
      ps[ct] += __shfl_xor(ps[ct], 32);
      pd[ct] += __shfl_xor(pd[ct], 16);
      pd[ct] += __shfl_xor(pd[ct], 32);
    }
    if (lg == 0 && rowok) {
      *(float4*)&ssrc[(size_t)row * 8] = make_float4(ps[0], ps[1], ps[2], ps[3]);
      *(float4*)&ssrc[(size_t)row * 8 + 4] = make_float4(ps[4], ps[5], ps[6], ps[7]);
      *(float4*)&sdst[(size_t)row * 8] = make_float4(pd[0], pd[1], pd[2], pd[3]);
      *(float4*)&sdst[(size_t)row * 8 + 4] = make_float4(pd[4], pd[5], pd[6], pd[7]);
    }
  } else {
    float ps = 0.f, pd = 0.f;
#pragma unroll
    for (int ct = 0; ct < 8; ++ct) {
      float4 av = *(const float4*)&asr[ct * 16 + lg * 4];
      float4 dv = *(const float4*)&adt[ct * 16 + lg * 4];
      ps += acc[ct][0] * av.x + acc[ct][1] * av.y + acc[ct][2] * av.z + acc[ct][3] * av.w;
      pd += acc[ct][0] * dv.x + acc[ct][1] * dv.y + acc[ct][2] * dv.z + acc[ct][3] * dv.w;
    }
    ps += __shfl_xor(ps, 16);
    ps += __shfl_xor(ps, 32);
    pd += __shfl_xor(pd, 16);
    pd += __shfl_xor(pd, 32);
    if (lg == 0 && rowok) {
      ssrc[row] = ps;
      sdst[row] = pd;
    }
  }
}

// ---------------- CSR build ----------------
__global__ void hist_kernel(const int* __restrict__ ei, int* __restrict__ deg, int nE, int nN) {
  int e = blockIdx.x * blockDim.x + threadIdx.x;
  if (e >= nE + nN) return;
  int dst = (e < nE) ? ei[nE + e] : (e - nE);
  atomicAdd(&deg[dst], 1);
}

__global__ __launch_bounds__(256) void scan1_kernel(const int* __restrict__ deg,
                                                    int* __restrict__ bsum, int n) {
  __shared__ int red[4];
  int b = blockIdx.x, tid = threadIdx.x;
  int lane = tid & 63, w = tid >> 6;
  int base = b * 1024 + tid * 4;
  int s = 0;
#pragma unroll
  for (int j = 0; j < 4; ++j) {
    int idx = base + j;
    if (idx < n) s += deg[idx];
  }
#pragma unroll
  for (int sh = 1; sh < 64; sh <<= 1) s += __shfl_xor(s, sh);
  if (lane == 0) red[w] = s;
  __syncthreads();
  if (tid == 0) bsum[b] = red[0] + red[1] + red[2] + red[3];
}

__global__ __launch_bounds__(64) void scan2_kernel(int* __restrict__ bsum, int* __restrict__ offs,
                                                   int nb, int n) {
  int lane = threadIdx.x;
  int carry = 0;
  for (int base = 0; base < nb; base += 64) {
    int v = (base + lane < nb) ? bsum[base + lane] : 0;
    int x = v;
#pragma unroll
    for (int s = 1; s < 64; s <<= 1) {
      int t = __shfl_up(x, s);
      if (lane >= s) x += t;
    }
    if (base + lane < nb) bsum[base + lane] = carry + x - v;  // exclusive
    carry += __shfl(x, 63);
  }
  if (lane == 0) offs[n] = carry;
}

__global__ __launch_bounds__(256) void scan3_kernel(const int* __restrict__ deg,
                                                    const int* __restrict__ bsum,
                                                    int* __restrict__ offs, int n) {
  __shared__ int wsum[4];
  int b = blockIdx.x, tid = threadIdx.x;
  int lane = tid & 63, w = tid >> 6;
  int base = b * 1024 + tid * 4;
  int v[4];
  int t = 0;
#pragma unroll
  for (int j = 0; j < 4; ++j) {
    int idx = base + j;
    v[j] = (idx < n) ? deg[idx] : 0;
    t += v[j];
  }
  int x = t;
#pragma unroll
  for (int s = 1; s < 64; s <<= 1) {
    int tt = __shfl_up(x, s);
    if (lane >= s) x += tt;
  }
  if (lane == 63) wsum[w] = x;
  __syncthreads();
  int woff = 0;
#pragma unroll
  for (int ww = 0; ww < 4; ++ww)
    if (ww < w) woff += wsum[ww];
  int off = bsum[b] + woff + x - t;
#pragma unroll
  for (int j = 0; j < 4; ++j) {
    int idx = base + j;
    if (idx < n) offs[idx] = off;
    off += v[j];
  }
}

__global__ void fill_kernel(const int* __restrict__ ei, const int* __restrict__ offs,
                            int* __restrict__ cursor, int* __restrict__ csr, int nE, int nN) {
  int e = blockIdx.x * blockDim.x + threadIdx.x;
  if (e >= nE + nN) return;
  int src, dst;
  if (e < nE) {
    src = ei[e];
    dst = ei[nE + e];
  } else {
    src = dst = e - nE;
  }
  int pos = atomicAdd(&cursor[dst], 1);
  csr[offs[dst] + pos] = src;
}

// ---------------- aggregation (fused softmax): one wave per dst node ----------------
__global__ __launch_bounds__(256) void agg1_kernel(const ushort* __restrict__ h1,
                                                   const int* __restrict__ csr,
                                                   const int* __restrict__ offs,
                                                   const float* __restrict__ ssrc,
                                                   const float* __restrict__ sdst,
                                                   const float* __restrict__ bias,
                                                   float* __restrict__ out, int nN) {
  int wid = (blockIdx.x * blockDim.x + threadIdx.x) >> 6;
  int lane = threadIdx.x & 63;
  if (wid >= nN) return;
  int c = lane * 2;
  int h = lane >> 3;
  float sd = sdst[wid * 8 + h];
  float n0 = 0.f, n1 = 0.f, den = 0.f;
  int beg = offs[wid], end = offs[wid + 1];
  int i = beg;
  for (; i + 3 < end; i += 4) {
    int s0 = csr[i], s1 = csr[i + 1], s2 = csr[i + 2], s3 = csr[i + 3];
    float e0 = ssrc[s0 * 8 + h];
    float e1 = ssrc[s1 * 8 + h];
    float e2 = ssrc[s2 * 8 + h];
    float e3 = ssrc[s3 * 8 + h];
    ushort2 u0 = *(const ushort2*)&h1[(size_t)s0 * 128 + c];
    ushort2 u1 = *(const ushort2*)&h1[(size_t)s1 * 128 + c];
    ushort2 u2 = *(const ushort2*)&h1[(size_t)s2 * 128 + c];
    ushort2 u3 = *(const ushort2*)&h1[(size_t)s3 * 128 + c];
    float a0 = __expf(leaky02(e0 + sd));
    float a1 = __expf(leaky02(e1 + sd));
    float a2 = __expf(leaky02(e2 + sd));
    float a3 = __expf(leaky02(e3 + sd));
    n0 += a0 * bf2f(u0.x) + a1 * bf2f(u1.x) + a2 * bf2f(u2.x) + a3 * bf2f(u3.x);
    n1 += a0 * bf2f(u0.y) + a1 * bf2f(u1.y) + a2 * bf2f(u2.y) + a3 * bf2f(u3.y);
    den += (a0 + a1) + (a2 + a3);
  }
  for (; i < end; ++i) {
    int s0 = csr[i];
    float e0 = ssrc[s0 * 8 + h];
    ushort2 u0 = *(const ushort2*)&h1[(size_t)s0 * 128 + c];
    float a0 = __expf(leaky02(e0 + sd));
    n0 += a0 * bf2f(u0.x);
    n1 += a0 * bf2f(u0.y);
    den += a0;
  }
  float invd = 1.0f / (den + 1e-16f);
  *(float2*)&out[(size_t)wid * 128 + c] =
      make_float2(n0 * invd + bias[c], n1 * invd + bias[c + 1]);
}

__global__ __launch_bounds__(256) void agg2_kernel(const ushort* __restrict__ h2,
                                                   const int* __restrict__ csr,
                                                   const int* __restrict__ offs,
                                                   const float* __restrict__ ssrc,
                                                   const float* __restrict__ sdst,
                                                   const float* __restrict__ bias,
                                                   float* __restrict__ out, int nN) {
  int wid = (blockIdx.x * blockDim.x + threadIdx.x) >> 6;
  int lane = threadIdx.x & 63;
  if (wid >= nN) return;
  int c = lane * 2;
  float sd = sdst[wid];
  float n0 = 0.f, n1 = 0.f, den = 0.f;
  int beg = offs[wid], end = offs[wid + 1];
  int i = beg;
  for (; i + 3 < end; i += 4) {
    int s0 = csr[i], s1 = csr[i + 1], s2 = csr[i + 2], s3 = csr[i + 3];
    float e0 = ssrc[s0];
    float e1 = ssrc[s1];
    float e2 = ssrc[s2];
    float e3 = ssrc[s3];
    ushort2 u0 = *(const ushort2*)&h2[(size_t)s0 * 128 + c];
    ushort2 u1 = *(const ushort2*)&h2[(size_t)s1 * 128 + c];
    ushort2 u2 = *(const ushort2*)&h2[(size_t)s2 * 128 + c];
    ushort2 u3 = *(const ushort2*)&h2[(size_t)s3 * 128 + c];
    float a0 = __expf(leaky02(e0 + sd));
    float a1 = __expf(leaky02(e1 + sd));
    float a2 = __expf(leaky02(e2 + sd));
    float a3 = __expf(leaky02(e3 + sd));
    n0 += a0 * bf2f(u0.x) + a1 * bf2f(u1.x) + a2 * bf2f(u2.x) + a3 * bf2f(u3.x);
    n1 += a0 * bf2f(u0.y) + a1 * bf2f(u1.y) + a2 * bf2f(u2.y) + a3 * bf2f(u3.y);
    den += (a0 + a1) + (a2 + a3);
  }
  for (; i < end; ++i) {
    int s0 = csr[i];
    float e0 = ssrc[s0];
    ushort2 u0 = *(const ushort2*)&h2[(size_t)s0 * 128 + c];
    float a0 = __expf(leaky02(e0 + sd));
    n0 += a0 * bf2f(u0.x);
    n1 += a0 * bf2f(u0.y);
    den += a0;
  }
  float invd = 1.0f / (den + 1e-16f);
  *(float2*)&out[(size_t)wid * 128 + c] =
      make_float2(n0 * invd + bias[c], n1 * invd + bias[c + 1]);
}

// ---------------- column stats (sum, sumsq) for BatchNorm: 64 rows/block ----------------
__global__ __launch_bounds__(256) void stats_kernel(const float* __restrict__ X,
                                                    float* __restrict__ stats, int n) {
  __shared__ float red[256];
  int tid = threadIdx.x;
  int c = tid & 127;
  int half = tid >> 7;
  float s = 0.f, sq = 0.f;
  int rbeg = (int)blockIdx.x * 64 + half;
  int rend = min((int)(blockIdx.x + 1) * 64, n);
#pragma unroll 4
  for (int r = rbeg; r < rend; r += 2) {
    float v = X[(size_t)r * 128 + c];
    s += v;
    sq += v * v;
  }
  red[tid] = s;
  __syncthreads();
  float s2 = (half == 0) ? s + red[tid + 128] : 0.f;
  __syncthreads();
  red[tid] = sq;
  __syncthreads();
  if (half == 0) {
    float sq2 = sq + red[tid + 128];
    atomicAdd(&stats[c], s2);
    atomicAdd(&stats[128 + c], sq2);
  }
}

// ---------------- BatchNorm (batch stats, biased var) + SELU ----------------
__global__ __launch_bounds__(256) void bnselu_kernel(const float* __restrict__ X,
                                                     const float* __restrict__ stats,
                                                     const float* __restrict__ gamma,
                                                     const float* __restrict__ beta,
                                                     float* __restrict__ Y, int n) {
  int gid = blockIdx.x * blockDim.x + threadIdx.x;
  if (gid >= n * 32) return;
  int c = (gid & 31) * 4;
  int r = gid >> 5;
  float invN = 1.0f / (float)n;
  float4 x = *(const float4*)&X[(size_t)r * 128 + c];
  float o[4];
#pragma unroll
  for (int j = 0; j < 4; ++j) {
    float xx = (j == 0) ? x.x : (j == 1) ? x.y : (j == 2) ? x.z : x.w;
    float mu = stats[c + j] * invN;
    float var = stats[128 + c + j] * invN - mu * mu;
    float rs = rsqrtf(var + 1e-5f);
    float y = gamma[c + j] * ((xx - mu) * rs) + beta[c + j];
    o[j] = selu_f(y);
  }
  *(float4*)&Y[(size_t)r * 128 + c] = make_float4(o[0], o[1], o[2], o[3]);
}

extern "C" void kernel_launch(void* const* d_in, const int* in_sizes, int n_in,
                              void* d_out, int out_size, void* d_ws, size_t ws_size,
                              hipStream_t stream) {
  const float* x   = (const float*)d_in[0];
  const int*   ei  = (const int*)d_in[1];
  // d_in[2] = edge_attr: unused (edge_dim=None)
  const float* W1  = (const float*)d_in[3];
  const float* as1 = (const float*)d_in[4];
  const float* ad1 = (const float*)d_in[5];
  const float* b1  = (const float*)d_in[6];
  const float* g1  = (const float*)d_in[7];
  const float* be1 = (const float*)d_in[8];
  const float* W2  = (const float*)d_in[9];
  const float* as2 = (const float*)d_in[10];
  const float* ad2 = (const float*)d_in[11];
  const float* b2  = (const float*)d_in[12];
  const float* g2  = (const float*)d_in[13];
  const float* be2 = (const float*)d_in[14];
  float* out = (float*)d_out;

  const int n  = in_sizes[0] / 128;   // 50000
  const int nE = in_sizes[1] / 2;     // 800000
  const int EA = nE + n;              // 850000
  const int nb = (n + 1023) / 1024;   // scan chunks

  float* ws = (float*)d_ws;
  size_t o = 0;
  float* Bf = ws + o;     o += (size_t)n * 128;   // fp32: agg output / BN input
  ushort* H = (ushort*)(ws + o); o += (size_t)n * 64;  // bf16 h (gather table, reused)
  float* ssrc1 = ws + o;  o += (size_t)n * 8;
  float* sdst1 = ws + o;  o += (size_t)n * 8;
  float* ssrc2 = ws + o;  o += n;
  float* sdst2 = ws + o;  o += n;
  ushort* Wp1 = (ushort*)(ws + o); o += 8192;     // 16384 bf16
  ushort* Wp2 = (ushort*)(ws + o); o += 8192;
  // ---- zero region start ----
  float* zbase = ws + o;
  float* stats1 = ws + o; o += 256;
  float* stats2 = ws + o; o += 256;
  int* deg    = (int*)(ws + o); o += n;
  int* cursor = (int*)(ws + o); o += n;
  size_t zwords = (size_t)((ws + o) - zbase);
  // ---- zero region end ----
  int* offs = (int*)(ws + o); o += (size_t)n + 1;
  int* csr  = (int*)(ws + o); o += EA;
  int* bsum = (int*)(ws + o); o += nb;

  hipMemsetAsync(zbase, 0, zwords * sizeof(float), stream);

  // CSR build (shared by both layers) + weight pack
  hist_kernel<<<(EA + 255) / 256, 256, 0, stream>>>(ei, deg, nE, n);
  scan1_kernel<<<nb, 256, 0, stream>>>(deg, bsum, n);
  scan2_kernel<<<1, 64, 0, stream>>>(bsum, offs, nb, n);
  scan3_kernel<<<nb, 256, 0, stream>>>(deg, bsum, offs, n);
  fill_kernel<<<(EA + 255) / 256, 256, 0, stream>>>(ei, offs, cursor, csr, nE, n);
  pack_kernel<<<128, 256, 0, stream>>>(W1, W2, Wp1, Wp2);

  // ---- layer 1 (GEMM + fused scores) ----
  gemm_mfma_kernel<8, false><<<(n + 63) / 64, 256, 0, stream>>>(
      x, Wp1, H, as1, ad1, ssrc1, sdst1, n, nullptr, nullptr, nullptr);
  agg1_kernel<<<(n + 3) / 4, 256, 0, stream>>>(H, csr, offs, ssrc1, sdst1, b1, Bf, n);
  stats_kernel<<<(n + 63) / 64, 256, 0, stream>>>(Bf, stats1, n);

  // ---- layer 2 (BN+SELU fused into GEMM2 X load; GEMM + fused scores) ----
  gemm_mfma_kernel<1, true><<<(n + 63) / 64, 256, 0, stream>>>(
      Bf, Wp2, H, as2, ad2, ssrc2, sdst2, n, stats1, g1, be1);
  agg2_kernel<<<(n + 3) / 4, 256, 0, stream>>>(H, csr, offs, ssrc2, sdst2, b2, out, n);
  stats_kernel<<<(n + 63) / 64, 256, 0, stream>>>(out, stats2, n);
  bnselu_kernel<<<(n * 32 + 255) / 256, 256, 0, stream>>>(out, stats2, g2, be2, out, n);
}